// Round 1
// baseline (86.320 us; speedup 1.0000x reference)
//
#include <hip/hip_runtime.h>
#include <hip/hip_bf16.h>

#define NQ 10
#define DIM 1024          // 2^NQ
#define QDEPTH 4
#define BLK 256

__global__ __launch_bounds__(BLK) void hybrid_kernel(
    const float* __restrict__ x,      // (B,10)
    const float* __restrict__ Ws,     // (5,10,10)
    const float* __restrict__ bs,     // (5,10)
    const float* __restrict__ theta,  // (4,10)
    const float* __restrict__ Wf,     // (2,20)
    const float* __restrict__ bfin,   // (2,)
    float* __restrict__ out)          // (B,2)
{
    const int b   = blockIdx.x;
    const int tid = threadIdx.x;

    __shared__ float sre[DIM];
    __shared__ float sim[DIM];
    __shared__ float cs[NQ], sn[NQ];          // cos/sin(x/2) per qubit
    __shared__ float cth[QDEPTH*NQ], sth[QDEPTH*NQ]; // cos/sin(theta/2)
    __shared__ float zq[NQ];                  // <Z_q>
    __shared__ float hbuf[NQ];                // MLP activations
    __shared__ float cls[NQ];                 // final classical layer out
    __shared__ float redbuf[4*NQ];            // per-wave reduction partials

    // --- per-block precompute: RX half-angles for this sample, RY tables ---
    if (tid < NQ) {
        float xv = x[b*NQ + tid];
        cs[tid] = cosf(0.5f*xv);
        sn[tid] = sinf(0.5f*xv);
    }
    if (tid < QDEPTH*NQ) {
        float th = 0.5f * theta[tid];
        cth[tid] = cosf(th);
        sth[tid] = sinf(th);
    }
    __syncthreads();

    // --- initial state: amp(k) = (-i)^popc(k) * prod_q (bit_q ? sin : cos) ---
    #pragma unroll
    for (int kk = 0; kk < DIM/BLK; ++kk) {
        int k = tid + kk*BLK;
        float r = 1.0f;
        #pragma unroll
        for (int q = 0; q < NQ; ++q)
            r *= ((k >> q) & 1) ? sn[q] : cs[q];
        int p = __popc(k) & 3;
        // (-i)^p : p=0 -> (1,0), 1 -> (0,-1), 2 -> (-1,0), 3 -> (0,1)
        sre[k] = (p == 0) ? r : ((p == 2) ? -r : 0.0f);
        sim[k] = (p == 1) ? -r : ((p == 3) ? r : 0.0f);
    }
    __syncthreads();

    // --- circuit: per layer, 10 RY gates + CZ-chain sign ---
    for (int l = 0; l < QDEPTH; ++l) {
        for (int q = 0; q < NQ; ++q) {
            const float ct = cth[l*NQ + q];
            const float st = sth[l*NQ + q];
            const int mask = (1 << q) - 1;
            #pragma unroll
            for (int pp = 0; pp < 2; ++pp) {
                int p  = tid + pp*BLK;                    // pair index 0..511
                int i0 = ((p & ~mask) << 1) | (p & mask); // bit q = 0
                int i1 = i0 | (1 << q);                   // bit q = 1
                float a0r = sre[i0], a0i = sim[i0];
                float a1r = sre[i1], a1i = sim[i1];
                sre[i0] = ct*a0r - st*a1r;
                sim[i0] = ct*a0i - st*a1i;
                sre[i1] = st*a0r + ct*a1r;
                sim[i1] = st*a0i + ct*a1i;
            }
            __syncthreads();
        }
        // CZ(q,q+1) chain: sign = parity of popc(k & (k>>1)) over adjacent pairs
        #pragma unroll
        for (int kk = 0; kk < DIM/BLK; ++kk) {
            int k = tid + kk*BLK;
            if (__popc(k & (k >> 1)) & 1) { sre[k] = -sre[k]; sim[k] = -sim[k]; }
        }
        __syncthreads();
    }

    // --- Z expectations: zq[q] = sum_k |amp_k|^2 * (1 - 2*bit_q(k)) ---
    float acc[NQ];
    #pragma unroll
    for (int q = 0; q < NQ; ++q) acc[q] = 0.0f;
    #pragma unroll
    for (int kk = 0; kk < DIM/BLK; ++kk) {
        int k = tid + kk*BLK;
        float pr = sre[k]*sre[k] + sim[k]*sim[k];
        #pragma unroll
        for (int q = 0; q < NQ; ++q)
            acc[q] += ((k >> q) & 1) ? -pr : pr;
    }
    #pragma unroll
    for (int q = 0; q < NQ; ++q) {
        #pragma unroll
        for (int off = 32; off > 0; off >>= 1)
            acc[q] += __shfl_down(acc[q], off);
    }
    {
        int lane = tid & 63, wv = tid >> 6;
        if (lane == 0) {
            #pragma unroll
            for (int q = 0; q < NQ; ++q) redbuf[wv*NQ + q] = acc[q];
        }
    }
    __syncthreads();
    if (tid < NQ)
        zq[tid] = redbuf[tid] + redbuf[NQ + tid] + redbuf[2*NQ + tid] + redbuf[3*NQ + tid];

    // --- classical MLP (threads 0..9), runs after zq ready ---
    if (tid < NQ) hbuf[tid] = x[b*NQ + tid];
    __syncthreads();

    for (int l = 0; l < QDEPTH; ++l) {
        float v = 0.0f;
        if (tid < NQ) {
            v = bs[l*NQ + tid];
            #pragma unroll
            for (int j = 0; j < NQ; ++j)
                v += Ws[(l*NQ + tid)*NQ + j] * hbuf[j];
            v = fmaxf(v, 0.0f);
        }
        __syncthreads();
        if (tid < NQ) hbuf[tid] = v;
        __syncthreads();
    }
    if (tid < NQ) {
        float v = bs[4*NQ + tid];
        #pragma unroll
        for (int j = 0; j < NQ; ++j)
            v += Ws[(4*NQ + tid)*NQ + j] * hbuf[j];
        cls[tid] = v;
    }
    __syncthreads();

    // --- final linear: out = [cls, qfeat] @ Wf^T + bfin; qfeat[i] = zq[9-i] ---
    if (tid < 2) {
        float v = bfin[tid];
        #pragma unroll
        for (int j = 0; j < NQ; ++j) v += Wf[tid*20 + j] * cls[j];
        #pragma unroll
        for (int j = 0; j < NQ; ++j) v += Wf[tid*20 + 10 + j] * zq[9 - j];
        out[b*2 + tid] = v;
    }
}

extern "C" void kernel_launch(void* const* d_in, const int* in_sizes, int n_in,
                              void* d_out, int out_size, void* d_ws, size_t ws_size,
                              hipStream_t stream) {
    const float* x     = (const float*)d_in[0];   // (4096,10)
    const float* Ws    = (const float*)d_in[1];   // (5,10,10)
    const float* bs    = (const float*)d_in[2];   // (5,10)
    const float* theta = (const float*)d_in[3];   // (4,10)
    const float* Wf    = (const float*)d_in[4];   // (2,20)
    const float* bfin  = (const float*)d_in[5];   // (2,)
    float* out = (float*)d_out;

    const int B = in_sizes[0] / NQ;               // 4096
    hybrid_kernel<<<B, BLK, 0, stream>>>(x, Ws, bs, theta, Wf, bfin, out);
}

// Round 2
// 46.935 us; speedup vs baseline: 1.8392x; 1.8392x over previous
//
#include <hip/hip_runtime.h>
#include <hip/hip_bf16.h>
#include <math.h>

#define NQ 10
#define QDEPTH 4
#define BLK 256
#define WPS 4            // waves (samples) per block

__global__ __launch_bounds__(BLK) void hybrid_kernel(
    const float* __restrict__ x,      // (B,10)
    const float* __restrict__ Ws,     // (5,10,10)
    const float* __restrict__ bs,     // (5,10)
    const float* __restrict__ theta,  // (4,10)
    const float* __restrict__ Wf,     // (2,20)
    const float* __restrict__ bfin,   // (2,)
    float* __restrict__ out)          // (B,2)
{
    const int tid  = threadIdx.x;
    const int lane = tid & 63;
    const int wv   = tid >> 6;
    const int s    = blockIdx.x * WPS + wv;   // sample index (grid sized exactly)

    __shared__ float cth[QDEPTH * NQ], sth[QDEPTH * NQ];  // cos/sin(theta/2)
    __shared__ float cxs[WPS][NQ], sxs[WPS][NQ];          // cos/sin(x/2) per sample

    // wave 0: theta trig (40 entries); wave 1: per-sample x trig (40 entries)
    if (tid < QDEPTH * NQ) {
        sincosf(0.5f * theta[tid], &sth[tid], &cth[tid]);
    }
    if (tid >= 64 && tid < 64 + WPS * NQ) {
        int t2 = tid - 64;
        int si = t2 / NQ, q = t2 % NQ;
        float xv = x[(blockIdx.x * WPS + si) * NQ + q];
        sincosf(0.5f * xv, &sxs[si][q], &cxs[si][q]);
    }
    __syncthreads();

    // ---- initial state in registers: lane holds k = (lane<<4) | loc, loc=0..15
    // amp_k = (-i)^popc(k) * prod_q (bit_q ? sin(x_q/2) : cos(x_q/2))
    float re[16], im[16];
    {
        float c[NQ], sn[NQ];
        #pragma unroll
        for (int q = 0; q < NQ; ++q) { c[q] = cxs[wv][q]; sn[q] = sxs[wv][q]; }
        float lf = 1.0f;
        #pragma unroll
        for (int q = 4; q < NQ; ++q)
            lf *= ((lane >> (q - 4)) & 1) ? sn[q] : c[q];
        int pl = __popc(lane);
        #pragma unroll
        for (int loc = 0; loc < 16; ++loc) {
            float r = lf;
            #pragma unroll
            for (int q = 0; q < 4; ++q)
                r *= ((loc >> q) & 1) ? sn[q] : c[q];
            int p = (pl + __popc(loc)) & 3;
            re[loc] = (p == 0) ? r : ((p == 2) ? -r : 0.0f);
            im[loc] = (p == 1) ? -r : ((p == 3) ? r : 0.0f);
        }
    }

    // CZ sign decomposition: parity = P1(loc) + (loc bit3)&(lane bit0) + P3(lane)
    const int   p3 = __popc(lane & (lane >> 1)) & 1;
    const float sA = p3 ? -1.0f : 1.0f;                       // loc bit3 == 0
    const float sB = ((p3 ^ (lane & 1)) & 1) ? -1.0f : 1.0f;  // loc bit3 == 1

    // ---- circuit: 4 layers x (10 RY + CZ chain), fully in registers
    #pragma unroll
    for (int l = 0; l < QDEPTH; ++l) {
        // local qubits 0..3: in-register butterflies
        #pragma unroll
        for (int q = 0; q < 4; ++q) {
            const float ct = cth[l * NQ + q], st = sth[l * NQ + q];
            #pragma unroll
            for (int pp = 0; pp < 8; ++pp) {
                int lo = pp & ((1 << q) - 1);
                int hi = pp >> q;
                int i0 = (hi << (q + 1)) | lo;
                int i1 = i0 | (1 << q);
                float a0 = re[i0], a1 = re[i1];
                re[i0] = ct * a0 - st * a1;
                re[i1] = st * a0 + ct * a1;
                float b0 = im[i0], b1 = im[i1];
                im[i0] = ct * b0 - st * b1;
                im[i1] = st * b0 + ct * b1;
            }
        }
        // cross qubits 4..9: lane-exchange butterflies (no barriers)
        #pragma unroll
        for (int q = 4; q < NQ; ++q) {
            const float ct  = cth[l * NQ + q], st = sth[l * NQ + q];
            const int   d   = 1 << (q - 4);
            const float sgn = ((lane >> (q - 4)) & 1) ? st : -st;
            #pragma unroll
            for (int r = 0; r < 16; ++r) {
                float o  = __shfl_xor(re[r], d, 64);
                re[r] = fmaf(ct, re[r], sgn * o);
                float oi = __shfl_xor(im[r], d, 64);
                im[r] = fmaf(ct, im[r], sgn * oi);
            }
        }
        // CZ(q,q+1) chain: compile-time sign per loc
        #pragma unroll
        for (int loc = 0; loc < 16; ++loc) {
            const int P1 = __popc(loc & (loc >> 1)) & 1;
            float sg = (loc & 8) ? (P1 ? -sB : sB) : (P1 ? -sA : sA);
            re[loc] *= sg;
            im[loc] *= sg;
        }
    }

    // ---- Z expectations
    float zr[NQ];
    {
        float a0 = 0, a1 = 0, a2 = 0, a3 = 0, tot = 0;
        #pragma unroll
        for (int loc = 0; loc < 16; ++loc) {
            float pr = re[loc] * re[loc] + im[loc] * im[loc];
            tot += pr;
            a0 += (loc & 1) ? -pr : pr;
            a1 += (loc & 2) ? -pr : pr;
            a2 += (loc & 4) ? -pr : pr;
            a3 += (loc & 8) ? -pr : pr;
        }
        zr[0] = a0; zr[1] = a1; zr[2] = a2; zr[3] = a3;
        #pragma unroll
        for (int q = 4; q < NQ; ++q)
            zr[q] = ((lane >> (q - 4)) & 1) ? -tot : tot;
    }
    #pragma unroll
    for (int q = 0; q < NQ; ++q) {
        #pragma unroll
        for (int d = 1; d < 64; d <<= 1)
            zr[q] += __shfl_xor(zr[q], d, 64);
    }

    // ---- classical MLP on the same wave: lane i (<10) owns row i
    const int row = (lane < NQ) ? lane : 0;
    float h = x[s * NQ + row];
    #pragma unroll
    for (int l = 0; l < QDEPTH; ++l) {
        float v = bs[l * NQ + row];
        #pragma unroll
        for (int j = 0; j < NQ; ++j)
            v = fmaf(Ws[(l * NQ + row) * NQ + j], __shfl(h, j, 64), v);
        h = fmaxf(v, 0.0f);
    }
    float cls = bs[QDEPTH * NQ + row];
    #pragma unroll
    for (int j = 0; j < NQ; ++j)
        cls = fmaf(Ws[(QDEPTH * NQ + row) * NQ + j], __shfl(h, j, 64), cls);

    // ---- final linear: out = [cls, zq[9-i]] @ Wf^T + bfin (all lanes redundant)
    float o0 = bfin[0], o1 = bfin[1];
    #pragma unroll
    for (int j = 0; j < NQ; ++j) {
        float cj = __shfl(cls, j, 64);
        o0 = fmaf(Wf[j],      cj, o0);
        o1 = fmaf(Wf[20 + j], cj, o1);
    }
    #pragma unroll
    for (int j = 0; j < NQ; ++j) {
        float zj = zr[9 - j];
        o0 = fmaf(Wf[10 + j], zj, o0);
        o1 = fmaf(Wf[30 + j], zj, o1);
    }
    if (lane == 0) {
        out[s * 2 + 0] = o0;
        out[s * 2 + 1] = o1;
    }
}

extern "C" void kernel_launch(void* const* d_in, const int* in_sizes, int n_in,
                              void* d_out, int out_size, void* d_ws, size_t ws_size,
                              hipStream_t stream) {
    const float* x     = (const float*)d_in[0];   // (4096,10)
    const float* Ws    = (const float*)d_in[1];   // (5,10,10)
    const float* bs    = (const float*)d_in[2];   // (5,10)
    const float* theta = (const float*)d_in[3];   // (4,10)
    const float* Wf    = (const float*)d_in[4];   // (2,20)
    const float* bfin  = (const float*)d_in[5];   // (2,)
    float* out = (float*)d_out;

    const int B = in_sizes[0] / NQ;               // 4096
    hybrid_kernel<<<B / WPS, BLK, 0, stream>>>(x, Ws, bs, theta, Wf, bfin, out);
}

// Round 5
// 39.665 us; speedup vs baseline: 2.1762x; 1.1833x over previous
//
#include <hip/hip_runtime.h>
#include <math.h>

#define NQ 10
#define QDEPTH 4
#define BLK 256
#define WPS 4            // waves (samples) per block

__device__ __forceinline__ int   asi(float v) { return __builtin_bit_cast(int, v); }
__device__ __forceinline__ float asf(int v)   { return __builtin_bit_cast(float, v); }

// lane^1 / lane^2 via DPP quad_perm (pure VALU)
#define XOR1(v) asf(__builtin_amdgcn_update_dpp(asi(v), asi(v), 0xB1, 0xF, 0xF, true))
#define XOR2(v) asf(__builtin_amdgcn_update_dpp(asi(v), asi(v), 0x4E, 0xF, 0xF, true))
// lane^4 / lane^8 via ds_swizzle (DS pipe, no address VGPR)
#define XOR4(v) asf(__builtin_amdgcn_ds_swizzle(asi(v), 0x101F))
#define XOR8(v) asf(__builtin_amdgcn_ds_swizzle(asi(v), 0x201F))

// v + v[lane^16] / v + v[lane^32] — gfx950 permlane swaps (VALU), order-of-outputs independent
__device__ __forceinline__ float xsum16(float v) {
#if __has_builtin(__builtin_amdgcn_permlane16_swap)
    unsigned u = (unsigned)asi(v);
    auto r = __builtin_amdgcn_permlane16_swap(u, u, false, false);
    return asf((int)r[0]) + asf((int)r[1]);
#else
    return v + asf(__builtin_amdgcn_ds_swizzle(asi(v), 0x401F));
#endif
}
__device__ __forceinline__ float xsum32(float v) {
#if __has_builtin(__builtin_amdgcn_permlane32_swap)
    unsigned u = (unsigned)asi(v);
    auto r = __builtin_amdgcn_permlane32_swap(u, u, false, false);
    return asf((int)r[0]) + asf((int)r[1]);
#else
    return v + __shfl_xor(v, 32, 64);
#endif
}
__device__ __forceinline__ float rlane(float v, int l) {
    return asf(__builtin_amdgcn_readlane(asi(v), l));
}

__global__ __launch_bounds__(BLK, 4) void hybrid_kernel(
    const float* __restrict__ x,      // (B,10)
    const float* __restrict__ Ws,     // (5,10,10)
    const float* __restrict__ bs,     // (5,10)
    const float* __restrict__ theta,  // (4,10)
    const float* __restrict__ Wf,     // (2,20)
    const float* __restrict__ bfin,   // (2,)
    float* __restrict__ out)          // (B,2)
{
    const int tid  = threadIdx.x;
    const int lane = tid & 63;
    const int wv   = tid >> 6;
    const int s    = blockIdx.x * WPS + wv;   // sample index

    // ---- trig table in lanes: lanes 0..39 = theta gates, 40..49 = this sample's x
    float ang = 0.0f;
    if (lane < QDEPTH * NQ)              ang = theta[lane];
    else if (lane < QDEPTH * NQ + NQ)    ang = x[s * NQ + (lane - QDEPTH * NQ)];
    float sv, cv;
    sincosf(0.5f * ang, &sv, &cv);

    // ---- u-coordinates: u_k = i^popc(k) * amp_k. Init u = prod(cos/sin) (REAL).
    // RY gate in u-coords: u0' = c*u0 + i*s*u1 ; u1' = c*u1 + i*s*u0  (symmetric!)
    // => re' = c*re - s*im_partner ; im' = c*im + s*re_partner  (no per-lane sign)
    float cq[NQ], sq[NQ];
    #pragma unroll
    for (int q = 0; q < NQ; ++q) {
        cq[q] = rlane(cv, QDEPTH * NQ + q);
        sq[q] = rlane(sv, QDEPTH * NQ + q);
    }
    float lf = 1.0f;
    #pragma unroll
    for (int b = 0; b < 6; ++b)
        lf *= ((lane >> b) & 1) ? sq[4 + b] : cq[4 + b];

    float re[16], im[16];
    {
        float p01[4], p23[4];
        p01[0] = cq[0] * cq[1]; p01[1] = sq[0] * cq[1];
        p01[2] = cq[0] * sq[1]; p01[3] = sq[0] * sq[1];
        p23[0] = cq[2] * cq[3]; p23[1] = sq[2] * cq[3];
        p23[2] = cq[2] * sq[3]; p23[3] = sq[2] * sq[3];
        #pragma unroll
        for (int loc = 0; loc < 16; ++loc) {
            re[loc] = lf * p01[loc & 3] * p23[loc >> 2];
            im[loc] = 0.0f;
        }
    }

    // CZ sign decomposition (k = (lane<<4)|loc): parity = P1(loc) ^ (locbit3 & lanebit0) ^ P3(lane)
    const int   p3v = __popc(lane & (lane >> 1)) & 1;
    const float sAv = p3v ? -1.0f : 1.0f;
    const float sBv = ((p3v ^ (lane & 1)) & 1) ? -1.0f : 1.0f;

    // ---- circuit
    #pragma unroll
    for (int l = 0; l < QDEPTH; ++l) {
        // local qubits 0..3 (register butterflies)
        #pragma unroll
        for (int q = 0; q < 4; ++q) {
            const float ct = rlane(cv, l * NQ + q);
            const float st = rlane(sv, l * NQ + q);
            #pragma unroll
            for (int pp = 0; pp < 8; ++pp) {
                int lo = pp & ((1 << q) - 1);
                int i0 = ((pp >> q) << (q + 1)) | lo;
                int i1 = i0 | (1 << q);
                float r0 = re[i0], r1 = re[i1], m0 = im[i0], m1 = im[i1];
                re[i0] = fmaf(-st, m1, ct * r0);
                im[i0] = fmaf( st, r1, ct * m0);
                re[i1] = fmaf(-st, m0, ct * r1);
                im[i1] = fmaf( st, r0, ct * m1);
            }
        }
        // cross qubits 4..7: exact partner exchange (DPP / swizzle)
        #pragma unroll
        for (int q = 4; q < 8; ++q) {
            const float ct = rlane(cv, l * NQ + q);
            const float st = rlane(sv, l * NQ + q);
            #pragma unroll
            for (int r = 0; r < 16; ++r) {
                float rp, ip;
                if      (q == 4) { rp = XOR1(re[r]); ip = XOR1(im[r]); }
                else if (q == 5) { rp = XOR2(re[r]); ip = XOR2(im[r]); }
                else if (q == 6) { rp = XOR4(re[r]); ip = XOR4(im[r]); }
                else             { rp = XOR8(re[r]); ip = XOR8(im[r]); }
                re[r] = fmaf(-st, ip, ct * re[r]);
                im[r] = fmaf( st, rp, ct * im[r]);
            }
        }
        // cross qubits 8,9 via permlane swap-sums: partner = (sum) - own
        #pragma unroll
        for (int q = 8; q < NQ; ++q) {
            const float ct = rlane(cv, l * NQ + q);
            const float st = rlane(sv, l * NQ + q);
            #pragma unroll
            for (int r = 0; r < 16; ++r) {
                float rs = (q == 8) ? xsum16(re[r]) : xsum32(re[r]);
                float is = (q == 8) ? xsum16(im[r]) : xsum32(im[r]);
                float t1 = fmaf( st, im[r], ct * re[r]);   // c*re + s*im
                float t2 = fmaf(-st, re[r], ct * im[r]);   // c*im - s*re
                re[r] = fmaf(-st, is, t1);                 // = c*re - s*(is-im)
                im[r] = fmaf( st, rs, t2);                 // = c*im + s*(rs-re)
            }
        }
        // CZ chain (diagonal signs, unchanged by u-transform)
        #pragma unroll
        for (int loc = 0; loc < 16; ++loc) {
            const int P1 = __popc(loc & (loc >> 1)) & 1;
            float sg = (loc & 8) ? (P1 ? -sBv : sBv) : (P1 ? -sAv : sAv);
            re[loc] *= sg;
            im[loc] *= sg;
        }
    }

    // ---- Z expectations: |u|^2 == |amp|^2
    float zr[NQ];
    {
        float a0 = 0, a1 = 0, a2 = 0, a3 = 0, tot = 0;
        #pragma unroll
        for (int loc = 0; loc < 16; ++loc) {
            float pr = fmaf(re[loc], re[loc], im[loc] * im[loc]);
            tot += pr;
            a0 += (loc & 1) ? -pr : pr;
            a1 += (loc & 2) ? -pr : pr;
            a2 += (loc & 4) ? -pr : pr;
            a3 += (loc & 8) ? -pr : pr;
        }
        zr[0] = a0; zr[1] = a1; zr[2] = a2; zr[3] = a3;
        #pragma unroll
        for (int q = 4; q < NQ; ++q)
            zr[q] = ((lane >> (q - 4)) & 1) ? -tot : tot;
    }
    #pragma unroll
    for (int q = 0; q < NQ; ++q) {
        float v = zr[q];
        v += XOR1(v);
        v += XOR2(v);
        v += XOR4(v);
        v += XOR8(v);
        v  = xsum16(v);
        v  = xsum32(v);
        zr[q] = v;
    }

    // ---- classical MLP: lane i (<10) owns row i; broadcasts via readlane
    const int row = (lane < NQ) ? lane : 0;
    float h = x[s * NQ + row];
    #pragma unroll
    for (int l = 0; l < QDEPTH; ++l) {
        float v = bs[l * NQ + row];
        #pragma unroll
        for (int j = 0; j < NQ; ++j)
            v = fmaf(Ws[(l * NQ + row) * NQ + j], rlane(h, j), v);
        h = fmaxf(v, 0.0f);
    }
    float cls = bs[QDEPTH * NQ + row];
    #pragma unroll
    for (int j = 0; j < NQ; ++j)
        cls = fmaf(Ws[(QDEPTH * NQ + row) * NQ + j], rlane(h, j), cls);

    // ---- final linear: out = [cls, zq[9-i]] @ Wf^T + bfin
    float o0 = bfin[0], o1 = bfin[1];
    #pragma unroll
    for (int j = 0; j < NQ; ++j) {
        float cj = rlane(cls, j);
        o0 = fmaf(Wf[j],      cj, o0);
        o1 = fmaf(Wf[20 + j], cj, o1);
    }
    #pragma unroll
    for (int j = 0; j < NQ; ++j) {
        float zj = zr[9 - j];
        o0 = fmaf(Wf[10 + j], zj, o0);
        o1 = fmaf(Wf[30 + j], zj, o1);
    }
    if (lane == 0) {
        out[s * 2 + 0] = o0;
        out[s * 2 + 1] = o1;
    }
}

extern "C" void kernel_launch(void* const* d_in, const int* in_sizes, int n_in,
                              void* d_out, int out_size, void* d_ws, size_t ws_size,
                              hipStream_t stream) {
    const float* x     = (const float*)d_in[0];   // (4096,10)
    const float* Ws    = (const float*)d_in[1];   // (5,10,10)
    const float* bs    = (const float*)d_in[2];   // (5,10)
    const float* theta = (const float*)d_in[3];   // (4,10)
    const float* Wf    = (const float*)d_in[4];   // (2,20)
    const float* bfin  = (const float*)d_in[5];   // (2,)
    float* out = (float*)d_out;

    const int B = in_sizes[0] / NQ;               // 4096
    hybrid_kernel<<<B / WPS, BLK, 0, stream>>>(x, Ws, bs, theta, Wf, bfin, out);
}

// Round 6
// 25.543 us; speedup vs baseline: 3.3795x; 1.5529x over previous
//
#include <hip/hip_runtime.h>
#include <math.h>

#define NQ 10
#define QDEPTH 4
#define BLK 256
#define WPS 4            // waves (samples) per block

typedef float v2f __attribute__((ext_vector_type(2)));

__device__ __forceinline__ int   asi(float v) { return __builtin_bit_cast(int, v); }
__device__ __forceinline__ float asf(int v)   { return __builtin_bit_cast(float, v); }

// exact lane^D partner exchange; D=1,2 DPP (VALU), D=4,8,16 ds_swizzle, D=32 ds_bpermute
template<int D>
__device__ __forceinline__ float exch(float v, int addr32) {
    if constexpr (D == 1)
        return asf(__builtin_amdgcn_update_dpp(asi(v), asi(v), 0xB1, 0xF, 0xF, true));
    else if constexpr (D == 2)
        return asf(__builtin_amdgcn_update_dpp(asi(v), asi(v), 0x4E, 0xF, 0xF, true));
    else if constexpr (D == 4)
        return asf(__builtin_amdgcn_ds_swizzle(asi(v), 0x101F));
    else if constexpr (D == 8)
        return asf(__builtin_amdgcn_ds_swizzle(asi(v), 0x201F));
    else if constexpr (D == 16)
        return asf(__builtin_amdgcn_ds_swizzle(asi(v), 0x401F));
    else
        return asf(__builtin_amdgcn_ds_bpermute(addr32, asi(v)));
}

__device__ __forceinline__ float rlane(float v, int l) {
    return asf(__builtin_amdgcn_readlane(asi(v), l));
}

// cross-qubit RY in real coords: P' = ct*P + stv*P_partner (same coef for re & im)
template<int D>
__device__ __forceinline__ void cross_gate(v2f (&P)[16], float ct, float stv, int addr32) {
    #pragma unroll
    for (int r = 0; r < 16; ++r) {
        v2f pp;
        pp.x = exch<D>(P[r].x, addr32);
        pp.y = exch<D>(P[r].y, addr32);
        P[r] = ct * P[r] + stv * pp;
    }
}

__global__ __launch_bounds__(BLK, 4) void hybrid_kernel(
    const float* __restrict__ x,      // (B,10)
    const float* __restrict__ Ws,     // (5,10,10)
    const float* __restrict__ bs,     // (5,10)
    const float* __restrict__ theta,  // (4,10)
    const float* __restrict__ Wf,     // (2,20)
    const float* __restrict__ bfin,   // (2,)
    float* __restrict__ out)          // (B,2)
{
    const int tid  = threadIdx.x;
    const int lane = tid & 63;
    const int wv   = tid >> 6;
    const int s    = blockIdx.x * WPS + wv;   // sample index

    // ---- trig via lanes: 0..39 theta gates, 40..49 this sample's x
    float ang = 0.0f;
    if (lane < QDEPTH * NQ)              ang = theta[lane];
    else if (lane < QDEPTH * NQ + NQ)    ang = x[s * NQ + (lane - QDEPTH * NQ)];
    float sv_, cv_;
    sincosf(0.5f * ang, &sv_, &cv_);

    float cq[NQ], sq[NQ];
    #pragma unroll
    for (int q = 0; q < NQ; ++q) {
        cq[q] = rlane(cv_, QDEPTH * NQ + q);
        sq[q] = rlane(sv_, QDEPTH * NQ + q);
    }
    float lf = 1.0f;
    #pragma unroll
    for (int b = 0; b < 6; ++b)
        lf *= ((lane >> b) & 1) ? sq[4 + b] : cq[4 + b];

    // ---- init in ORIGINAL coords: amp_k = (-i)^popc(k) * r_k (real/imag disjoint)
    // re,im evolve independently under the real circuit -> pack P[loc] = (re, im)
    const int pl = __popc(lane);
    v2f P[16];
    {
        float p01[4], p23[4];
        p01[0] = cq[0] * cq[1]; p01[1] = sq[0] * cq[1];
        p01[2] = cq[0] * sq[1]; p01[3] = sq[0] * sq[1];
        p23[0] = cq[2] * cq[3]; p23[1] = sq[2] * cq[3];
        p23[2] = cq[2] * sq[3]; p23[3] = sq[2] * sq[3];
        #pragma unroll
        for (int loc = 0; loc < 16; ++loc) {
            float r = lf * p01[loc & 3] * p23[loc >> 2];
            int pm = (pl + __popc(loc)) & 3;   // (-i)^pm
            float re = (pm == 0) ? r : ((pm == 2) ? -r : 0.0f);
            float im = (pm == 1) ? -r : ((pm == 3) ? r : 0.0f);
            P[loc].x = re;
            P[loc].y = im;
        }
    }

    // ---- per-lane bit masks
    int zmask[6];
    #pragma unroll
    for (int b = 0; b < 6; ++b)
        zmask[b] = ((lane >> b) & 1) << 31;     // sign-flip word when lane bit set
    const int addr32 = (lane ^ 32) << 2;        // ds_bpermute byte address

    // CZ sign words: par(k) = P1(loc) ^ (locbit3 & lanebit0) ^ P3(lane)
    const int p3  = __popc(lane & (lane >> 1)) & 1;
    const int sAw = p3 << 31;
    const int sBw = (p3 ^ (lane & 1)) << 31;
    const int sAn = sAw ^ 0x80000000;
    const int sBn = sBw ^ 0x80000000;

    // ---- circuit: 4 x (10 RY + CZ chain), real coords, zero barriers
    for (int l = 0; l < QDEPTH; ++l) {
        // local qubits 0..3: register butterflies (pure 2-wide SIMD, pk-able)
        #pragma unroll
        for (int q = 0; q < 4; ++q) {
            const float ct = rlane(cv_, l * NQ + q);
            const float st = rlane(sv_, l * NQ + q);
            #pragma unroll
            for (int pp = 0; pp < 8; ++pp) {
                int i0 = ((pp >> q) << (q + 1)) | (pp & ((1 << q) - 1));
                int i1 = i0 | (1 << q);
                v2f a = P[i0], b = P[i1];
                P[i0] = ct * a - st * b;
                P[i1] = st * a + ct * b;
            }
        }
        // cross qubits 4..9: stv = (lane bit ? +st : -st)
        {
            float ct, stv;
            ct  = rlane(cv_, l * NQ + 4);
            stv = asf(asi(-rlane(sv_, l * NQ + 4)) ^ zmask[0]);
            cross_gate<1>(P, ct, stv, addr32);
            ct  = rlane(cv_, l * NQ + 5);
            stv = asf(asi(-rlane(sv_, l * NQ + 5)) ^ zmask[1]);
            cross_gate<2>(P, ct, stv, addr32);
            ct  = rlane(cv_, l * NQ + 6);
            stv = asf(asi(-rlane(sv_, l * NQ + 6)) ^ zmask[2]);
            cross_gate<4>(P, ct, stv, addr32);
            ct  = rlane(cv_, l * NQ + 7);
            stv = asf(asi(-rlane(sv_, l * NQ + 7)) ^ zmask[3]);
            cross_gate<8>(P, ct, stv, addr32);
            ct  = rlane(cv_, l * NQ + 8);
            stv = asf(asi(-rlane(sv_, l * NQ + 8)) ^ zmask[4]);
            cross_gate<16>(P, ct, stv, addr32);
            ct  = rlane(cv_, l * NQ + 9);
            stv = asf(asi(-rlane(sv_, l * NQ + 9)) ^ zmask[5]);
            cross_gate<32>(P, ct, stv, addr32);
        }
        // CZ chain: sign-bit XOR (compile-time select among 4 precomputed words)
        #pragma unroll
        for (int loc = 0; loc < 16; ++loc) {
            const int C1 = __popc(loc & (loc >> 1)) & 1;
            const int m  = (loc & 8) ? (C1 ? sBn : sBw) : (C1 ? sAn : sAw);
            P[loc].x = asf(asi(P[loc].x) ^ m);
            P[loc].y = asf(asi(P[loc].y) ^ m);
        }
    }

    // ---- probs + folded quantum->output contraction
    // out_t += sum_k p_k * w_t(k),  w_t(k) = L_t(lane) + T_t[loc]
    // coef for zq[q] in out_t is Wf[t*20 + 19 - q]
    float pr[16], S = 0.0f;
    #pragma unroll
    for (int loc = 0; loc < 16; ++loc) {
        pr[loc] = fmaf(P[loc].x, P[loc].x, P[loc].y * P[loc].y);
        S += pr[loc];
    }
    float d0 = 0.0f, d1 = 0.0f;
    #pragma unroll
    for (int loc = 0; loc < 16; ++loc) {
        float t0 = ((loc & 1) ? -Wf[19] : Wf[19]) + ((loc & 2) ? -Wf[18] : Wf[18])
                 + ((loc & 4) ? -Wf[17] : Wf[17]) + ((loc & 8) ? -Wf[16] : Wf[16]);
        float t1 = ((loc & 1) ? -Wf[39] : Wf[39]) + ((loc & 2) ? -Wf[38] : Wf[38])
                 + ((loc & 4) ? -Wf[37] : Wf[37]) + ((loc & 8) ? -Wf[36] : Wf[36]);
        d0 = fmaf(t0, pr[loc], d0);
        d1 = fmaf(t1, pr[loc], d1);
    }
    float L0 = 0.0f, L1 = 0.0f;
    #pragma unroll
    for (int b = 0; b < 6; ++b) {      // q = 4+b -> Wf[15-b] / Wf[35-b]
        L0 += asf(asi(Wf[15 - b]) ^ zmask[b]);
        L1 += asf(asi(Wf[35 - b]) ^ zmask[b]);
    }
    float qp0 = fmaf(L0, S, d0);
    float qp1 = fmaf(L1, S, d1);
    // reduce the 2 partials across 64 lanes
    qp0 += exch<1>(qp0, addr32);  qp1 += exch<1>(qp1, addr32);
    qp0 += exch<2>(qp0, addr32);  qp1 += exch<2>(qp1, addr32);
    qp0 += exch<4>(qp0, addr32);  qp1 += exch<4>(qp1, addr32);
    qp0 += exch<8>(qp0, addr32);  qp1 += exch<8>(qp1, addr32);
    qp0 += exch<16>(qp0, addr32); qp1 += exch<16>(qp1, addr32);
    qp0 += exch<32>(qp0, addr32); qp1 += exch<32>(qp1, addr32);

    // ---- classical MLP: lane i (<10) owns row i; broadcasts via readlane
    const int row = (lane < NQ) ? lane : 0;
    float h = x[s * NQ + row];
    #pragma unroll
    for (int l = 0; l < QDEPTH; ++l) {
        float v = bs[l * NQ + row];
        #pragma unroll
        for (int j = 0; j < NQ; ++j)
            v = fmaf(Ws[(l * NQ + row) * NQ + j], rlane(h, j), v);
        h = fmaxf(v, 0.0f);
    }
    float cls = bs[QDEPTH * NQ + row];
    #pragma unroll
    for (int j = 0; j < NQ; ++j)
        cls = fmaf(Ws[(QDEPTH * NQ + row) * NQ + j], rlane(h, j), cls);

    // ---- final linear
    float o0 = bfin[0] + qp0, o1 = bfin[1] + qp1;
    #pragma unroll
    for (int j = 0; j < NQ; ++j) {
        float cj = rlane(cls, j);
        o0 = fmaf(Wf[j],      cj, o0);
        o1 = fmaf(Wf[20 + j], cj, o1);
    }
    if (lane == 0) {
        float2 o; o.x = o0; o.y = o1;
        *reinterpret_cast<float2*>(&out[s * 2]) = o;
    }
}

extern "C" void kernel_launch(void* const* d_in, const int* in_sizes, int n_in,
                              void* d_out, int out_size, void* d_ws, size_t ws_size,
                              hipStream_t stream) {
    const float* x     = (const float*)d_in[0];   // (4096,10)
    const float* Ws    = (const float*)d_in[1];   // (5,10,10)
    const float* bs    = (const float*)d_in[2];   // (5,10)
    const float* theta = (const float*)d_in[3];   // (4,10)
    const float* Wf    = (const float*)d_in[4];   // (2,20)
    const float* bfin  = (const float*)d_in[5];   // (2,)
    float* out = (float*)d_out;

    const int B = in_sizes[0] / NQ;               // 4096
    hybrid_kernel<<<B / WPS, BLK, 0, stream>>>(x, Ws, bs, theta, Wf, bfin, out);
}